// Round 1
// baseline (563.562 us; speedup 1.0000x reference)
//
#include <hip/hip_runtime.h>

#define N_NODES 50000
#define N_EDGES 800000
#define N_GRAPHS 256
#define D 128

// ---------------- CSR build ----------------

__global__ __launch_bounds__(256) void k_count(const int* __restrict__ ei, int* __restrict__ cnt) {
    int e = blockIdx.x * 256 + threadIdx.x;
    if (e < N_EDGES) atomicAdd(&cnt[ei[N_EDGES + e]], 1);   // dst row
}

__global__ __launch_bounds__(256) void k_dinv(const int* __restrict__ cnt, float* __restrict__ dinv) {
    int i = blockIdx.x * 256 + threadIdx.x;
    if (i < N_NODES) dinv[i] = rsqrtf((float)(cnt[i] + 1));  // +1 self loop
}

__global__ __launch_bounds__(1024) void k_scan(const int* __restrict__ cnt, int* __restrict__ row_ptr) {
    __shared__ int part[1024];
    int tid = threadIdx.x;
    const int CH = (N_NODES + 1023) / 1024;   // 49
    int lo = tid * CH;
    int hi = lo + CH; if (hi > N_NODES) hi = N_NODES;
    if (lo > N_NODES) lo = N_NODES;
    int s = 0;
    for (int i = lo; i < hi; ++i) s += cnt[i];
    part[tid] = s;
    __syncthreads();
    for (int off = 1; off < 1024; off <<= 1) {
        int v = (tid >= off) ? part[tid - off] : 0;
        __syncthreads();
        part[tid] += v;
        __syncthreads();
    }
    int excl = (tid == 0) ? 0 : part[tid - 1];
    for (int i = lo; i < hi; ++i) { row_ptr[i] = excl; excl += cnt[i]; }
    if (tid == 0) row_ptr[N_NODES] = N_EDGES;
}

__global__ __launch_bounds__(256) void k_fill(const int* __restrict__ ei, const int* __restrict__ row_ptr,
                                              int* __restrict__ fill, int* __restrict__ col) {
    int e = blockIdx.x * 256 + threadIdx.x;
    if (e < N_EDGES) {
        int d = ei[N_EDGES + e];
        int s = ei[e];
        int p = atomicAdd(&fill[d], 1);
        col[row_ptr[d] + p] = s;
    }
}

__global__ __launch_bounds__(512) void k_bounds(const int* __restrict__ batch, int* __restrict__ gstart) {
    int g = threadIdx.x;
    if (g > N_GRAPHS) return;
    int lo = 0, hi = N_NODES;            // lower_bound(batch, g)
    while (lo < hi) { int mid = (lo + hi) >> 1; if (batch[mid] < g) lo = mid + 1; else hi = mid; }
    gstart[g] = lo;
}

// ---------------- dense transform: T = act(A) @ W ----------------
// act: ACT ? relu(a + bias[k]) : a   (bias indexed by input feature k)

template<bool ACT>
__global__ __launch_bounds__(256) void k_gemm(const float* __restrict__ A, const float* __restrict__ Wm,
                                              const float* __restrict__ bias, float* __restrict__ T) {
    __shared__ float As[64][132];        // 33.8 KB, padded
    int tid = threadIdx.x;
    int r0blk = blockIdx.x * 64;

    #pragma unroll
    for (int it = 0; it < 8; ++it) {
        int idx = it * 256 + tid;        // 2048 float4 = 64 rows x 32
        int row = idx >> 5;
        int c4  = idx & 31;
        int gr = r0blk + row;
        float4 v = make_float4(0.f, 0.f, 0.f, 0.f);
        if (gr < N_NODES) v = reinterpret_cast<const float4*>(A)[gr * 32 + c4];
        if (ACT) {
            int c = c4 * 4;
            v.x = fmaxf(v.x + bias[c + 0], 0.f);
            v.y = fmaxf(v.y + bias[c + 1], 0.f);
            v.z = fmaxf(v.z + bias[c + 2], 0.f);
            v.w = fmaxf(v.w + bias[c + 3], 0.f);
        }
        *reinterpret_cast<float4*>(&As[row][c4 * 4]) = v;
    }
    __syncthreads();

    int tx = tid & 31, ty = tid >> 5;    // tx: col group (4 cols), ty: row group (8 rows)
    int r0 = ty * 8;
    float acc[8][4];
    #pragma unroll
    for (int i = 0; i < 8; ++i)
        #pragma unroll
        for (int j = 0; j < 4; ++j) acc[i][j] = 0.f;

    const float4* W4 = reinterpret_cast<const float4*>(Wm);
    #pragma unroll 4
    for (int k = 0; k < D; ++k) {
        float4 w = W4[k * 32 + tx];
        float a[8];
        #pragma unroll
        for (int i = 0; i < 8; ++i) a[i] = As[r0 + i][k];   // half-wave broadcast
        #pragma unroll
        for (int i = 0; i < 8; ++i) {
            acc[i][0] = fmaf(a[i], w.x, acc[i][0]);
            acc[i][1] = fmaf(a[i], w.y, acc[i][1]);
            acc[i][2] = fmaf(a[i], w.z, acc[i][2]);
            acc[i][3] = fmaf(a[i], w.w, acc[i][3]);
        }
    }

    float4* T4 = reinterpret_cast<float4*>(T);
    #pragma unroll
    for (int i = 0; i < 8; ++i) {
        int gr = r0blk + r0 + i;
        if (gr < N_NODES)
            T4[gr * 32 + tx] = make_float4(acc[i][0], acc[i][1], acc[i][2], acc[i][3]);
    }
}

// ---------------- pull aggregation: AGG[i] = dinv[i]^2*T[i] + sum_j dinv[s]*dinv[i]*T[s] ----------------
// one wave per node, 64 lanes x float2 = 128 dims

__global__ __launch_bounds__(256) void k_agg(const float* __restrict__ T, float* __restrict__ AGG,
                                             const int* __restrict__ row_ptr, const int* __restrict__ col,
                                             const float* __restrict__ dinv) {
    int node = blockIdx.x * 4 + (threadIdx.x >> 6);
    int lane = threadIdx.x & 63;
    if (node >= N_NODES) return;
    const float2* Tv = reinterpret_cast<const float2*>(T);

    float di = dinv[node];
    float2 acc = Tv[(size_t)node * 64 + lane];
    acc.x *= di * di; acc.y *= di * di;               // self loop

    int beg = row_ptr[node], end = row_ptr[node + 1];
    int j = beg;
    for (; j + 1 < end; j += 2) {
        int s0 = col[j], s1 = col[j + 1];
        float w0 = dinv[s0] * di;
        float w1 = dinv[s1] * di;
        float2 t0 = Tv[(size_t)s0 * 64 + lane];
        float2 t1 = Tv[(size_t)s1 * 64 + lane];
        acc.x = fmaf(w0, t0.x, acc.x); acc.y = fmaf(w0, t0.y, acc.y);
        acc.x = fmaf(w1, t1.x, acc.x); acc.y = fmaf(w1, t1.y, acc.y);
    }
    if (j < end) {
        int s0 = col[j];
        float w0 = dinv[s0] * di;
        float2 t0 = Tv[(size_t)s0 * 64 + lane];
        acc.x = fmaf(w0, t0.x, acc.x); acc.y = fmaf(w0, t0.y, acc.y);
    }
    reinterpret_cast<float2*>(AGG)[(size_t)node * 64 + lane] = acc;
}

// ---------------- pool: out[g] = (sum_i agg[i] + cnt*b3) / max(cnt,1) ----------------

__global__ __launch_bounds__(128) void k_pool(const float* __restrict__ AGG, const float* __restrict__ b3,
                                              const int* __restrict__ gstart, float* __restrict__ out) {
    int g = blockIdx.x;
    int c = threadIdx.x;
    int beg = gstart[g], end = gstart[g + 1];
    float acc = 0.f;
    #pragma unroll 4
    for (int i = beg; i < end; ++i) acc += AGG[(size_t)i * D + c];
    int cnt = end - beg;
    float denom = (float)(cnt > 0 ? cnt : 1);
    out[g * D + c] = (acc + (float)cnt * b3[c]) / denom;
}

// ---------------- launch ----------------

static inline size_t align256(size_t x) { return (x + 255) & ~(size_t)255; }

extern "C" void kernel_launch(void* const* d_in, const int* in_sizes, int n_in,
                              void* d_out, int out_size, void* d_ws, size_t ws_size,
                              hipStream_t stream) {
    const float* x    = (const float*)d_in[0];
    const int*  ei    = (const int*)d_in[1];
    const int*  batch = (const int*)d_in[2];
    const float* W1 = (const float*)d_in[3];
    const float* b1 = (const float*)d_in[4];
    const float* W2 = (const float*)d_in[5];
    const float* b2 = (const float*)d_in[6];
    const float* W3 = (const float*)d_in[7];
    const float* b3 = (const float*)d_in[8];
    float* out = (float*)d_out;

    char* ws = (char*)d_ws;
    size_t off = 0;
    auto alloc = [&](size_t bytes) { void* p = ws + off; off = align256(off + bytes); return p; };
    int*   cnt     = (int*)  alloc((size_t)N_NODES * 4);
    int*   fill    = (int*)  alloc((size_t)N_NODES * 4);
    int*   row_ptr = (int*)  alloc((size_t)(N_NODES + 1) * 4);
    int*   col     = (int*)  alloc((size_t)N_EDGES * 4);
    float* dinv    = (float*)alloc((size_t)N_NODES * 4);
    int*   gstart  = (int*)  alloc((size_t)(N_GRAPHS + 1) * 4);
    float* T       = (float*)alloc((size_t)N_NODES * D * 4);
    float* AGG     = (float*)alloc((size_t)N_NODES * D * 4);
    (void)ws_size; (void)in_sizes; (void)n_in; (void)out_size;

    hipMemsetAsync(cnt, 0, (size_t)N_NODES * 4, stream);
    hipMemsetAsync(fill, 0, (size_t)N_NODES * 4, stream);

    k_count <<<(N_EDGES + 255) / 256, 256, 0, stream>>>(ei, cnt);
    k_dinv  <<<(N_NODES + 255) / 256, 256, 0, stream>>>(cnt, dinv);
    k_scan  <<<1, 1024, 0, stream>>>(cnt, row_ptr);
    k_fill  <<<(N_EDGES + 255) / 256, 256, 0, stream>>>(ei, row_ptr, fill, col);
    k_bounds<<<1, 512, 0, stream>>>(batch, gstart);

    const int gemm_grid = (N_NODES + 63) / 64;
    const int agg_grid  = (N_NODES + 3) / 4;

    k_gemm<false><<<gemm_grid, 256, 0, stream>>>(x,   W1, nullptr, T);
    k_agg        <<<agg_grid,  256, 0, stream>>>(T, AGG, row_ptr, col, dinv);
    k_gemm<true ><<<gemm_grid, 256, 0, stream>>>(AGG, W2, b1, T);
    k_agg        <<<agg_grid,  256, 0, stream>>>(T, AGG, row_ptr, col, dinv);
    k_gemm<true ><<<gemm_grid, 256, 0, stream>>>(AGG, W3, b2, T);
    k_agg        <<<agg_grid,  256, 0, stream>>>(T, AGG, row_ptr, col, dinv);
    k_pool       <<<N_GRAPHS, 128, 0, stream>>>(AGG, b3, gstart, out);
}

// Round 2
// 498.909 us; speedup vs baseline: 1.1296x; 1.1296x over previous
//
#include <hip/hip_runtime.h>

#define N_NODES 50000
#define N_EDGES 800000
#define N_GRAPHS 256
#define D 128
#define NBLK ((N_NODES + 255) / 256)   // 196 scan blocks

// ---------------- CSR build ----------------

__global__ __launch_bounds__(256) void k_count(const int* __restrict__ ei, int* __restrict__ cnt) {
    int e = blockIdx.x * 256 + threadIdx.x;
    if (e < N_EDGES) atomicAdd(&cnt[ei[N_EDGES + e]], 1);   // dst row
}

__device__ inline int wave_incl_scan(int x, int lane) {
    #pragma unroll
    for (int d = 1; d < 64; d <<= 1) {
        int n = __shfl_up(x, d);
        if (lane >= d) x += n;
    }
    return x;
}

// per-block sum of cnt (coalesced) + fused dinv
__global__ __launch_bounds__(256) void k_blocksum(const int* __restrict__ cnt, int* __restrict__ bsum,
                                                  float* __restrict__ dinv) {
    int i = blockIdx.x * 256 + threadIdx.x;
    int v = (i < N_NODES) ? cnt[i] : 0;
    if (i < N_NODES) dinv[i] = rsqrtf((float)(v + 1));       // +1 self loop
    int lane = threadIdx.x & 63, w = threadIdx.x >> 6;
    int s = v;
    #pragma unroll
    for (int d = 32; d > 0; d >>= 1) s += __shfl_down(s, d);
    __shared__ int ws[4];
    if (lane == 0) ws[w] = s;
    __syncthreads();
    if (threadIdx.x == 0) bsum[blockIdx.x] = ws[0] + ws[1] + ws[2] + ws[3];
}

// single small block: exclusive scan of the 196 block sums
__global__ __launch_bounds__(256) void k_scanbase(const int* __restrict__ bsum, int* __restrict__ bbase) {
    int t = threadIdx.x;
    int v = (t < NBLK) ? bsum[t] : 0;
    int lane = t & 63, w = t >> 6;
    int incl = wave_incl_scan(v, lane);
    __shared__ int ws[4];
    if (lane == 63) ws[w] = incl;
    __syncthreads();
    int add = 0;
    #pragma unroll
    for (int k = 0; k < 4; ++k) if (k < w) add += ws[k];
    if (t < NBLK) bbase[t] = add + incl - v;
}

// per-block exclusive scan + base -> row_ptr
__global__ __launch_bounds__(256) void k_rowptr(const int* __restrict__ cnt, const int* __restrict__ bbase,
                                                int* __restrict__ row_ptr) {
    int i = blockIdx.x * 256 + threadIdx.x;
    int v = (i < N_NODES) ? cnt[i] : 0;
    int lane = threadIdx.x & 63, w = threadIdx.x >> 6;
    int incl = wave_incl_scan(v, lane);
    __shared__ int ws[4];
    if (lane == 63) ws[w] = incl;
    __syncthreads();
    int add = bbase[blockIdx.x];
    #pragma unroll
    for (int k = 0; k < 4; ++k) if (k < w) add += ws[k];
    if (i < N_NODES) row_ptr[i] = add + incl - v;
    if (i == N_NODES) row_ptr[N_NODES] = N_EDGES;
}

__global__ __launch_bounds__(256) void k_fill(const int* __restrict__ ei, const int* __restrict__ row_ptr,
                                              int* __restrict__ fill, int* __restrict__ col) {
    int e = blockIdx.x * 256 + threadIdx.x;
    if (e < N_EDGES) {
        int d = ei[N_EDGES + e];
        int s = ei[e];
        int p = atomicAdd(&fill[d], 1);
        col[row_ptr[d] + p] = s;
    }
}

__global__ __launch_bounds__(512) void k_bounds(const int* __restrict__ batch, int* __restrict__ gstart) {
    int g = threadIdx.x;
    if (g > N_GRAPHS) return;
    int lo = 0, hi = N_NODES;            // lower_bound(batch, g)
    while (lo < hi) { int mid = (lo + hi) >> 1; if (batch[mid] < g) lo = mid + 1; else hi = mid; }
    gstart[g] = lo;
}

// ---------------- dense transform: T = act(A) @ W ----------------
// act: ACT ? relu(a + bias[k]) : a   (bias indexed by input feature k)

template<bool ACT>
__global__ __launch_bounds__(256) void k_gemm(const float* __restrict__ A, const float* __restrict__ Wm,
                                              const float* __restrict__ bias, float* __restrict__ T) {
    __shared__ float As[64][132];        // 33.8 KB, padded
    int tid = threadIdx.x;
    int r0blk = blockIdx.x * 64;

    #pragma unroll
    for (int it = 0; it < 8; ++it) {
        int idx = it * 256 + tid;        // 2048 float4 = 64 rows x 32
        int row = idx >> 5;
        int c4  = idx & 31;
        int gr = r0blk + row;
        float4 v = make_float4(0.f, 0.f, 0.f, 0.f);
        if (gr < N_NODES) v = reinterpret_cast<const float4*>(A)[gr * 32 + c4];
        if (ACT) {
            int c = c4 * 4;
            v.x = fmaxf(v.x + bias[c + 0], 0.f);
            v.y = fmaxf(v.y + bias[c + 1], 0.f);
            v.z = fmaxf(v.z + bias[c + 2], 0.f);
            v.w = fmaxf(v.w + bias[c + 3], 0.f);
        }
        *reinterpret_cast<float4*>(&As[row][c4 * 4]) = v;
    }
    __syncthreads();

    int tx = tid & 31, ty = tid >> 5;    // tx: col group (4 cols), ty: row group (8 rows)
    int r0 = ty * 8;
    float acc[8][4];
    #pragma unroll
    for (int i = 0; i < 8; ++i)
        #pragma unroll
        for (int j = 0; j < 4; ++j) acc[i][j] = 0.f;

    const float4* W4 = reinterpret_cast<const float4*>(Wm);
    #pragma unroll 4
    for (int k = 0; k < D; ++k) {
        float4 w = W4[k * 32 + tx];
        float a[8];
        #pragma unroll
        for (int i = 0; i < 8; ++i) a[i] = As[r0 + i][k];   // half-wave broadcast
        #pragma unroll
        for (int i = 0; i < 8; ++i) {
            acc[i][0] = fmaf(a[i], w.x, acc[i][0]);
            acc[i][1] = fmaf(a[i], w.y, acc[i][1]);
            acc[i][2] = fmaf(a[i], w.z, acc[i][2]);
            acc[i][3] = fmaf(a[i], w.w, acc[i][3]);
        }
    }

    float4* T4 = reinterpret_cast<float4*>(T);
    #pragma unroll
    for (int i = 0; i < 8; ++i) {
        int gr = r0blk + r0 + i;
        if (gr < N_NODES)
            T4[gr * 32 + tx] = make_float4(acc[i][0], acc[i][1], acc[i][2], acc[i][3]);
    }
}

// ---------------- pull aggregation: AGG[i] = dinv[i]^2*T[i] + sum_j dinv[s]*dinv[i]*T[s] ----------------
// one wave per node, 64 lanes x float2 = 128 dims

__global__ __launch_bounds__(256) void k_agg(const float* __restrict__ T, float* __restrict__ AGG,
                                             const int* __restrict__ row_ptr, const int* __restrict__ col,
                                             const float* __restrict__ dinv) {
    int node = blockIdx.x * 4 + (threadIdx.x >> 6);
    int lane = threadIdx.x & 63;
    if (node >= N_NODES) return;
    const float2* Tv = reinterpret_cast<const float2*>(T);

    float di = dinv[node];
    float2 acc = Tv[(size_t)node * 64 + lane];
    acc.x *= di * di; acc.y *= di * di;               // self loop

    int beg = row_ptr[node], end = row_ptr[node + 1];
    int j = beg;
    for (; j + 1 < end; j += 2) {
        int s0 = col[j], s1 = col[j + 1];
        float w0 = dinv[s0] * di;
        float w1 = dinv[s1] * di;
        float2 t0 = Tv[(size_t)s0 * 64 + lane];
        float2 t1 = Tv[(size_t)s1 * 64 + lane];
        acc.x = fmaf(w0, t0.x, acc.x); acc.y = fmaf(w0, t0.y, acc.y);
        acc.x = fmaf(w1, t1.x, acc.x); acc.y = fmaf(w1, t1.y, acc.y);
    }
    if (j < end) {
        int s0 = col[j];
        float w0 = dinv[s0] * di;
        float2 t0 = Tv[(size_t)s0 * 64 + lane];
        acc.x = fmaf(w0, t0.x, acc.x); acc.y = fmaf(w0, t0.y, acc.y);
    }
    reinterpret_cast<float2*>(AGG)[(size_t)node * 64 + lane] = acc;
}

// ---------------- pool: out[g] = (sum_i agg[i] + cnt*b3) / max(cnt,1) ----------------

__global__ __launch_bounds__(128) void k_pool(const float* __restrict__ AGG, const float* __restrict__ b3,
                                              const int* __restrict__ gstart, float* __restrict__ out) {
    int g = blockIdx.x;
    int c = threadIdx.x;
    int beg = gstart[g], end = gstart[g + 1];
    float acc = 0.f;
    #pragma unroll 4
    for (int i = beg; i < end; ++i) acc += AGG[(size_t)i * D + c];
    int cnt = end - beg;
    float denom = (float)(cnt > 0 ? cnt : 1);
    out[g * D + c] = (acc + (float)cnt * b3[c]) / denom;
}

// ---------------- launch ----------------

static inline size_t align256(size_t x) { return (x + 255) & ~(size_t)255; }

extern "C" void kernel_launch(void* const* d_in, const int* in_sizes, int n_in,
                              void* d_out, int out_size, void* d_ws, size_t ws_size,
                              hipStream_t stream) {
    const float* x    = (const float*)d_in[0];
    const int*  ei    = (const int*)d_in[1];
    const int*  batch = (const int*)d_in[2];
    const float* W1 = (const float*)d_in[3];
    const float* b1 = (const float*)d_in[4];
    const float* W2 = (const float*)d_in[5];
    const float* b2 = (const float*)d_in[6];
    const float* W3 = (const float*)d_in[7];
    const float* b3 = (const float*)d_in[8];
    float* out = (float*)d_out;

    char* ws = (char*)d_ws;
    size_t off = 0;
    auto alloc = [&](size_t bytes) { void* p = ws + off; off = align256(off + bytes); return p; };
    int*   cnt     = (int*)  alloc((size_t)N_NODES * 4);
    int*   fill    = (int*)  alloc((size_t)N_NODES * 4);
    int*   row_ptr = (int*)  alloc((size_t)(N_NODES + 1) * 4);
    int*   col     = (int*)  alloc((size_t)N_EDGES * 4);
    float* dinv    = (float*)alloc((size_t)N_NODES * 4);
    int*   gstart  = (int*)  alloc((size_t)(N_GRAPHS + 1) * 4);
    int*   bsum    = (int*)  alloc((size_t)NBLK * 4);
    int*   bbase   = (int*)  alloc((size_t)NBLK * 4);
    float* T       = (float*)alloc((size_t)N_NODES * D * 4);
    float* AGG     = (float*)alloc((size_t)N_NODES * D * 4);
    (void)ws_size; (void)in_sizes; (void)n_in; (void)out_size;

    hipMemsetAsync(cnt, 0, (size_t)N_NODES * 4, stream);
    hipMemsetAsync(fill, 0, (size_t)N_NODES * 4, stream);

    k_count   <<<(N_EDGES + 255) / 256, 256, 0, stream>>>(ei, cnt);
    k_blocksum<<<NBLK, 256, 0, stream>>>(cnt, bsum, dinv);
    k_scanbase<<<1, 256, 0, stream>>>(bsum, bbase);
    k_rowptr  <<<NBLK, 256, 0, stream>>>(cnt, bbase, row_ptr);
    k_fill    <<<(N_EDGES + 255) / 256, 256, 0, stream>>>(ei, row_ptr, fill, col);
    k_bounds  <<<1, 512, 0, stream>>>(batch, gstart);

    const int gemm_grid = (N_NODES + 63) / 64;
    const int agg_grid  = (N_NODES + 3) / 4;

    k_gemm<false><<<gemm_grid, 256, 0, stream>>>(x,   W1, nullptr, T);
    k_agg        <<<agg_grid,  256, 0, stream>>>(T, AGG, row_ptr, col, dinv);
    k_gemm<true ><<<gemm_grid, 256, 0, stream>>>(AGG, W2, b1, T);
    k_agg        <<<agg_grid,  256, 0, stream>>>(T, AGG, row_ptr, col, dinv);
    k_gemm<true ><<<gemm_grid, 256, 0, stream>>>(AGG, W3, b2, T);
    k_agg        <<<agg_grid,  256, 0, stream>>>(T, AGG, row_ptr, col, dinv);
    k_pool       <<<N_GRAPHS, 128, 0, stream>>>(AGG, b3, gstart, out);
}

// Round 3
// 390.657 us; speedup vs baseline: 1.4426x; 1.2771x over previous
//
#include <hip/hip_runtime.h>

#define N_NODES 50000
#define N_EDGES 800000
#define N_GRAPHS 256
#define D 128
#define NBLK ((N_NODES + 255) / 256)   // 196 scan blocks

// bf16 helpers (bit-exact RNE convert, no lib dependency)
__device__ inline unsigned short f2bf(float f) {
    unsigned u = __float_as_uint(f);
    u += 0x7FFF + ((u >> 16) & 1);     // round to nearest even
    return (unsigned short)(u >> 16);
}

// ---------------- CSR build ----------------

__global__ __launch_bounds__(256) void k_count(const int* __restrict__ ei, int* __restrict__ cnt) {
    int e = blockIdx.x * 256 + threadIdx.x;
    if (e < N_EDGES) atomicAdd(&cnt[ei[N_EDGES + e]], 1);   // dst row
}

__device__ inline int wave_incl_scan(int x, int lane) {
    #pragma unroll
    for (int d = 1; d < 64; d <<= 1) {
        int n = __shfl_up(x, d);
        if (lane >= d) x += n;
    }
    return x;
}

// per-block sum of cnt (coalesced) + fused dinv
__global__ __launch_bounds__(256) void k_blocksum(const int* __restrict__ cnt, int* __restrict__ bsum,
                                                  float* __restrict__ dinv) {
    int i = blockIdx.x * 256 + threadIdx.x;
    int v = (i < N_NODES) ? cnt[i] : 0;
    if (i < N_NODES) dinv[i] = rsqrtf((float)(v + 1));       // +1 self loop
    int lane = threadIdx.x & 63, w = threadIdx.x >> 6;
    int s = v;
    #pragma unroll
    for (int d = 32; d > 0; d >>= 1) s += __shfl_down(s, d);
    __shared__ int ws[4];
    if (lane == 0) ws[w] = s;
    __syncthreads();
    if (threadIdx.x == 0) bsum[blockIdx.x] = ws[0] + ws[1] + ws[2] + ws[3];
}

// single small block: exclusive scan of the 196 block sums
__global__ __launch_bounds__(256) void k_scanbase(const int* __restrict__ bsum, int* __restrict__ bbase) {
    int t = threadIdx.x;
    int v = (t < NBLK) ? bsum[t] : 0;
    int lane = t & 63, w = t >> 6;
    int incl = wave_incl_scan(v, lane);
    __shared__ int ws[4];
    if (lane == 63) ws[w] = incl;
    __syncthreads();
    int add = 0;
    #pragma unroll
    for (int k = 0; k < 4; ++k) if (k < w) add += ws[k];
    if (t < NBLK) bbase[t] = add + incl - v;
}

// per-block exclusive scan + base -> row_ptr
__global__ __launch_bounds__(256) void k_rowptr(const int* __restrict__ cnt, const int* __restrict__ bbase,
                                                int* __restrict__ row_ptr) {
    int i = blockIdx.x * 256 + threadIdx.x;
    int v = (i < N_NODES) ? cnt[i] : 0;
    int lane = threadIdx.x & 63, w = threadIdx.x >> 6;
    int incl = wave_incl_scan(v, lane);
    __shared__ int ws[4];
    if (lane == 63) ws[w] = incl;
    __syncthreads();
    int add = bbase[blockIdx.x];
    #pragma unroll
    for (int k = 0; k < 4; ++k) if (k < w) add += ws[k];
    if (i < N_NODES) row_ptr[i] = add + incl - v;
    if (i == N_NODES) row_ptr[N_NODES] = N_EDGES;
}

// fill col + fused per-edge norm weight (kills per-edge dinv gather in k_agg)
__global__ __launch_bounds__(256) void k_fill(const int* __restrict__ ei, const int* __restrict__ row_ptr,
                                              int* __restrict__ fill, int* __restrict__ col,
                                              const float* __restrict__ dinv, float* __restrict__ nrm) {
    int e = blockIdx.x * 256 + threadIdx.x;
    if (e < N_EDGES) {
        int d = ei[N_EDGES + e];
        int s = ei[e];
        int p = atomicAdd(&fill[d], 1);
        int pos = row_ptr[d] + p;
        col[pos] = s;
        nrm[pos] = dinv[s] * dinv[d];
    }
}

__global__ __launch_bounds__(512) void k_bounds(const int* __restrict__ batch, int* __restrict__ gstart) {
    int g = threadIdx.x;
    if (g > N_GRAPHS) return;
    int lo = 0, hi = N_NODES;            // lower_bound(batch, g)
    while (lo < hi) { int mid = (lo + hi) >> 1; if (batch[mid] < g) lo = mid + 1; else hi = mid; }
    gstart[g] = lo;
}

// ---------------- dense transform: T(bf16) = act(A) @ W ----------------
// act: ACT ? relu(a + bias[k]) : a   (bias indexed by input feature k)

template<bool ACT>
__global__ __launch_bounds__(256) void k_gemm(const float* __restrict__ A, const float* __restrict__ Wm,
                                              const float* __restrict__ bias, unsigned short* __restrict__ T) {
    __shared__ float As[64][132];        // 33.8 KB, padded
    int tid = threadIdx.x;
    int r0blk = blockIdx.x * 64;

    #pragma unroll
    for (int it = 0; it < 8; ++it) {
        int idx = it * 256 + tid;        // 2048 float4 = 64 rows x 32
        int row = idx >> 5;
        int c4  = idx & 31;
        int gr = r0blk + row;
        float4 v = make_float4(0.f, 0.f, 0.f, 0.f);
        if (gr < N_NODES) v = reinterpret_cast<const float4*>(A)[gr * 32 + c4];
        if (ACT) {
            int c = c4 * 4;
            v.x = fmaxf(v.x + bias[c + 0], 0.f);
            v.y = fmaxf(v.y + bias[c + 1], 0.f);
            v.z = fmaxf(v.z + bias[c + 2], 0.f);
            v.w = fmaxf(v.w + bias[c + 3], 0.f);
        }
        *reinterpret_cast<float4*>(&As[row][c4 * 4]) = v;
    }
    __syncthreads();

    int tx = tid & 31, ty = tid >> 5;    // tx: col group (4 cols), ty: row group (8 rows)
    int r0 = ty * 8;
    float acc[8][4];
    #pragma unroll
    for (int i = 0; i < 8; ++i)
        #pragma unroll
        for (int j = 0; j < 4; ++j) acc[i][j] = 0.f;

    const float4* W4 = reinterpret_cast<const float4*>(Wm);
    #pragma unroll 4
    for (int k = 0; k < D; ++k) {
        float4 w = W4[k * 32 + tx];
        float a[8];
        #pragma unroll
        for (int i = 0; i < 8; ++i) a[i] = As[r0 + i][k];   // half-wave broadcast
        #pragma unroll
        for (int i = 0; i < 8; ++i) {
            acc[i][0] = fmaf(a[i], w.x, acc[i][0]);
            acc[i][1] = fmaf(a[i], w.y, acc[i][1]);
            acc[i][2] = fmaf(a[i], w.z, acc[i][2]);
            acc[i][3] = fmaf(a[i], w.w, acc[i][3]);
        }
    }

    ushort4* T4 = reinterpret_cast<ushort4*>(T);   // 32 ushort4 per 128-col row
    #pragma unroll
    for (int i = 0; i < 8; ++i) {
        int gr = r0blk + r0 + i;
        if (gr < N_NODES) {
            ushort4 st;
            st.x = f2bf(acc[i][0]); st.y = f2bf(acc[i][1]);
            st.z = f2bf(acc[i][2]); st.w = f2bf(acc[i][3]);
            T4[(size_t)gr * 32 + tx] = st;
        }
    }
}

// ---------------- pull aggregation (bf16 gather, f32 accumulate) ----------------
// AGG[i] = dinv[i]^2*T[i] + sum_j nrm[j]*T[col[j]] ; one wave per node, lane = 2 cols

__global__ __launch_bounds__(256) void k_agg(const unsigned* __restrict__ Tu, float* __restrict__ AGG,
                                             const int* __restrict__ row_ptr, const int* __restrict__ col,
                                             const float* __restrict__ nrm, const float* __restrict__ dinv) {
    int node = blockIdx.x * 4 + (threadIdx.x >> 6);
    int lane = threadIdx.x & 63;
    if (node >= N_NODES) return;

    float di = dinv[node];
    unsigned ts = Tu[(size_t)node * 64 + lane];
    float w = di * di;
    float2 acc;
    acc.x = __uint_as_float(ts << 16) * w;                 // low bf16 = even col
    acc.y = __uint_as_float(ts & 0xFFFF0000u) * w;         // high bf16 = odd col

    int beg = row_ptr[node], end = row_ptr[node + 1];
    int j = beg;
    for (; j + 3 < end; j += 4) {
        int s0 = col[j], s1 = col[j + 1], s2 = col[j + 2], s3 = col[j + 3];
        float w0 = nrm[j], w1 = nrm[j + 1], w2 = nrm[j + 2], w3 = nrm[j + 3];
        unsigned t0 = Tu[(size_t)s0 * 64 + lane];
        unsigned t1 = Tu[(size_t)s1 * 64 + lane];
        unsigned t2 = Tu[(size_t)s2 * 64 + lane];
        unsigned t3 = Tu[(size_t)s3 * 64 + lane];
        acc.x = fmaf(w0, __uint_as_float(t0 << 16), acc.x);
        acc.y = fmaf(w0, __uint_as_float(t0 & 0xFFFF0000u), acc.y);
        acc.x = fmaf(w1, __uint_as_float(t1 << 16), acc.x);
        acc.y = fmaf(w1, __uint_as_float(t1 & 0xFFFF0000u), acc.y);
        acc.x = fmaf(w2, __uint_as_float(t2 << 16), acc.x);
        acc.y = fmaf(w2, __uint_as_float(t2 & 0xFFFF0000u), acc.y);
        acc.x = fmaf(w3, __uint_as_float(t3 << 16), acc.x);
        acc.y = fmaf(w3, __uint_as_float(t3 & 0xFFFF0000u), acc.y);
    }
    for (; j < end; ++j) {
        int s0 = col[j];
        float w0 = nrm[j];
        unsigned t0 = Tu[(size_t)s0 * 64 + lane];
        acc.x = fmaf(w0, __uint_as_float(t0 << 16), acc.x);
        acc.y = fmaf(w0, __uint_as_float(t0 & 0xFFFF0000u), acc.y);
    }
    reinterpret_cast<float2*>(AGG)[(size_t)node * 64 + lane] = acc;
}

// ---------------- pool: out[g] = (sum_i agg[i] + cnt*b3) / max(cnt,1) ----------------

__global__ __launch_bounds__(128) void k_pool(const float* __restrict__ AGG, const float* __restrict__ b3,
                                              const int* __restrict__ gstart, float* __restrict__ out) {
    int g = blockIdx.x;
    int c = threadIdx.x;
    int beg = gstart[g], end = gstart[g + 1];
    float acc = 0.f;
    #pragma unroll 4
    for (int i = beg; i < end; ++i) acc += AGG[(size_t)i * D + c];
    int cnt = end - beg;
    float denom = (float)(cnt > 0 ? cnt : 1);
    out[g * D + c] = (acc + (float)cnt * b3[c]) / denom;
}

// ---------------- launch ----------------

static inline size_t align256(size_t x) { return (x + 255) & ~(size_t)255; }

extern "C" void kernel_launch(void* const* d_in, const int* in_sizes, int n_in,
                              void* d_out, int out_size, void* d_ws, size_t ws_size,
                              hipStream_t stream) {
    const float* x    = (const float*)d_in[0];
    const int*  ei    = (const int*)d_in[1];
    const int*  batch = (const int*)d_in[2];
    const float* W1 = (const float*)d_in[3];
    const float* b1 = (const float*)d_in[4];
    const float* W2 = (const float*)d_in[5];
    const float* b2 = (const float*)d_in[6];
    const float* W3 = (const float*)d_in[7];
    const float* b3 = (const float*)d_in[8];
    float* out = (float*)d_out;

    char* ws = (char*)d_ws;
    size_t off = 0;
    auto alloc = [&](size_t bytes) { void* p = ws + off; off = align256(off + bytes); return p; };
    int*   cnt     = (int*)  alloc((size_t)N_NODES * 4);
    int*   fill    = (int*)  alloc((size_t)N_NODES * 4);
    int*   row_ptr = (int*)  alloc((size_t)(N_NODES + 1) * 4);
    int*   col     = (int*)  alloc((size_t)N_EDGES * 4);
    float* nrm     = (float*)alloc((size_t)N_EDGES * 4);
    float* dinv    = (float*)alloc((size_t)N_NODES * 4);
    int*   gstart  = (int*)  alloc((size_t)(N_GRAPHS + 1) * 4);
    int*   bsum    = (int*)  alloc((size_t)NBLK * 4);
    int*   bbase   = (int*)  alloc((size_t)NBLK * 4);
    unsigned short* T = (unsigned short*)alloc((size_t)N_NODES * D * 2);
    float* AGG     = (float*)alloc((size_t)N_NODES * D * 4);
    (void)ws_size; (void)in_sizes; (void)n_in; (void)out_size;

    hipMemsetAsync(cnt, 0, (size_t)N_NODES * 4, stream);
    hipMemsetAsync(fill, 0, (size_t)N_NODES * 4, stream);

    k_count   <<<(N_EDGES + 255) / 256, 256, 0, stream>>>(ei, cnt);
    k_blocksum<<<NBLK, 256, 0, stream>>>(cnt, bsum, dinv);
    k_scanbase<<<1, 256, 0, stream>>>(bsum, bbase);
    k_rowptr  <<<NBLK, 256, 0, stream>>>(cnt, bbase, row_ptr);
    k_fill    <<<(N_EDGES + 255) / 256, 256, 0, stream>>>(ei, row_ptr, fill, col, dinv, nrm);
    k_bounds  <<<1, 512, 0, stream>>>(batch, gstart);

    const int gemm_grid = (N_NODES + 63) / 64;
    const int agg_grid  = (N_NODES + 3) / 4;

    k_gemm<false><<<gemm_grid, 256, 0, stream>>>(x,   W1, nullptr, T);
    k_agg        <<<agg_grid,  256, 0, stream>>>((const unsigned*)T, AGG, row_ptr, col, nrm, dinv);
    k_gemm<true ><<<gemm_grid, 256, 0, stream>>>(AGG, W2, b1, T);
    k_agg        <<<agg_grid,  256, 0, stream>>>((const unsigned*)T, AGG, row_ptr, col, nrm, dinv);
    k_gemm<true ><<<gemm_grid, 256, 0, stream>>>(AGG, W3, b2, T);
    k_agg        <<<agg_grid,  256, 0, stream>>>((const unsigned*)T, AGG, row_ptr, col, nrm, dinv);
    k_pool       <<<N_GRAPHS, 128, 0, stream>>>(AGG, b3, gstart, out);
}